// Round 1
// baseline (58.327 us; speedup 1.0000x reference)
//
#include <hip/hip_runtime.h>
#include <math.h>

// ToRGB: y[b,o,p] = clip( sum_i coeff[b,o,i]*x[b,i,p] + bias[o], +-256 ) + upsample2(skip)
// x: (8,512,128,128) f32; out: (8,3,128,128) f32
// coeff[b,o,i] = weight[o,i]/512 * lrelu(w[b,:]@affine_w[i,:]*1/sqrt(512) + affine_b[i]) * sqrt(2)

#define IN_CH 512
#define OUT_CH 3
#define NPIX 16384    // 128*128
#define NB 8

// ---------------- Kernel 1: styles -> coeff (tiny) ----------------
__global__ __launch_bounds__(256) void coeff_kernel(
    const float* __restrict__ w, const float* __restrict__ aw,
    const float* __restrict__ ab, const float* __restrict__ wt,
    float* __restrict__ coeff) {
  const int b  = blockIdx.x >> 4;   // 8 batches
  const int rg = blockIdx.x & 15;   // 16 row-groups of 32 rows
  const int tid = threadIdx.x;
  __shared__ float wv[512];
  wv[tid]       = w[b * 512 + tid];
  wv[tid + 256] = w[b * 512 + 256 + tid];
  __syncthreads();
  const int wave = tid >> 6, lane = tid & 63;
  const float gain = 1.0f / sqrtf(512.0f);
  #pragma unroll 2
  for (int r = 0; r < 8; ++r) {
    const int i = rg * 32 + wave * 8 + r;
    const float* row = aw + (size_t)i * 512;
    float s = 0.f;
    #pragma unroll
    for (int k = 0; k < 8; ++k) s += row[lane + 64 * k] * wv[lane + 64 * k];
    #pragma unroll
    for (int off = 32; off >= 1; off >>= 1) s += __shfl_xor(s, off, 64);
    if (lane == 0) {
      float v = s * gain + ab[i];
      v = (v > 0.f ? v : 0.2f * v) * 1.41421356237f;  // lrelu * sqrt(2)
      #pragma unroll
      for (int o = 0; o < OUT_CH; ++o)
        coeff[b * (OUT_CH * IN_CH) + o * IN_CH + i] =
            wt[o * IN_CH + i] * (1.0f / 512.0f) * v;
    }
  }
}

// ---------------- Kernel 2: main reduction + epilogue ----------------
// grid: 8 batches * 256 pixel-groups (64 px each). block: 256 = 16 cols(x4 px) * 16 splits(32 ch)
__global__ __launch_bounds__(256) void main_kernel(
    const float* __restrict__ x, const float* __restrict__ coeff,
    const float* __restrict__ bias, const float* __restrict__ skip,
    float* __restrict__ out) {
  const int b   = blockIdx.x >> 8;
  const int g   = blockIdx.x & 255;
  const int p0  = g * 64;
  const int tid = threadIdx.x;
  const int col   = tid & 15;   // float4 column within 64-pixel group
  const int split = tid >> 4;   // channel split, 32 channels each

  // coeff staged per-split, padded to 100 floats (banks 0/4/8/12 per wave -> no conflict)
  __shared__ float lds_c[16 * 100];
  for (int idx = tid; idx < 1600; idx += 256) {
    int s = idx / 100, r = idx - s * 100;
    if (r < 96) {
      int k = r / 3, o = r - 3 * k;
      lds_c[idx] = coeff[b * (OUT_CH * IN_CH) + o * IN_CH + s * 32 + k];
    }
  }
  __syncthreads();

  const float* xp = x + ((size_t)(b * IN_CH + split * 32)) * NPIX + p0 + col * 4;
  const float* cp = lds_c + split * 100;

  float acc[12];
  #pragma unroll
  for (int j = 0; j < 12; ++j) acc[j] = 0.f;

  #pragma unroll 8
  for (int k = 0; k < 32; ++k) {
    float4 xv = *reinterpret_cast<const float4*>(xp);
    xp += NPIX;
    float c0 = cp[k * 3 + 0], c1 = cp[k * 3 + 1], c2 = cp[k * 3 + 2];
    acc[0] += c0 * xv.x; acc[1]  += c0 * xv.y; acc[2]  += c0 * xv.z; acc[3]  += c0 * xv.w;
    acc[4] += c1 * xv.x; acc[5]  += c1 * xv.y; acc[6]  += c1 * xv.z; acc[7]  += c1 * xv.w;
    acc[8] += c2 * xv.x; acc[9]  += c2 * xv.y; acc[10] += c2 * xv.z; acc[11] += c2 * xv.w;
  }

  // reduce 16 splits
  __shared__ float red[16][16][13];  // pad 13 to spread banks
  #pragma unroll
  for (int j = 0; j < 12; ++j) red[split][col][j] = acc[j];
  __syncthreads();
  #pragma unroll
  for (int s = 8; s >= 1; s >>= 1) {
    if (split < s) {
      #pragma unroll
      for (int j = 0; j < 12; ++j) red[split][col][j] += red[split + s][col][j];
    }
    __syncthreads();
  }

  // epilogue: 192 threads write 3 channels * 64 pixels
  if (tid < 192) {
    const int o = tid >> 6;
    const int l = tid & 63;
    const int p = p0 + l;
    float v = red[0][l >> 2][o * 4 + (l & 3)] + bias[o];
    v = fminf(fmaxf(v, -256.f), 256.f);

    // 2x upsample of skip with FIR [1,3,3,1]x[1,3,3,1]/16 (2x2 taps per output px)
    const int yy = p >> 7, xx = p & 127;
    int iy0, ix0; float wy0, wy1, wx0, wx1;
    if (yy & 1) { iy0 = (yy - 1) >> 1; wy0 = 3.f; wy1 = 1.f; }
    else        { iy0 = (yy >> 1) - 1; wy0 = 1.f; wy1 = 3.f; }
    if (xx & 1) { ix0 = (xx - 1) >> 1; wx0 = 3.f; wx1 = 1.f; }
    else        { ix0 = (xx >> 1) - 1; wx0 = 1.f; wx1 = 3.f; }

    const float* sp = skip + ((size_t)(b * OUT_CH + o)) * 4096;
    float s00 = (iy0 >= 0     && ix0 >= 0    ) ? sp[iy0 * 64 + ix0]           : 0.f;
    float s01 = (iy0 >= 0     && ix0 + 1 < 64) ? sp[iy0 * 64 + ix0 + 1]       : 0.f;
    float s10 = (iy0 + 1 < 64 && ix0 >= 0    ) ? sp[(iy0 + 1) * 64 + ix0]     : 0.f;
    float s11 = (iy0 + 1 < 64 && ix0 + 1 < 64) ? sp[(iy0 + 1) * 64 + ix0 + 1] : 0.f;
    float up = (wy0 * (wx0 * s00 + wx1 * s01) + wy1 * (wx0 * s10 + wx1 * s11)) * (1.f / 16.f);

    out[((size_t)(b * OUT_CH + o)) * NPIX + p] = v + up;
  }
}

extern "C" void kernel_launch(void* const* d_in, const int* in_sizes, int n_in,
                              void* d_out, int out_size, void* d_ws, size_t ws_size,
                              hipStream_t stream) {
  const float* x        = (const float*)d_in[0];
  const float* w        = (const float*)d_in[1];
  const float* skip     = (const float*)d_in[2];
  const float* affine_w = (const float*)d_in[3];
  const float* affine_b = (const float*)d_in[4];
  const float* weight   = (const float*)d_in[5];
  const float* bias     = (const float*)d_in[6];
  float* out   = (float*)d_out;
  float* coeff = (float*)d_ws;  // 8*3*512 floats = 48 KB

  coeff_kernel<<<128, 256, 0, stream>>>(w, affine_w, affine_b, weight, coeff);
  main_kernel<<<NB * 256, 256, 0, stream>>>(x, coeff, bias, skip, out);
}

// Round 2
// 53.610 us; speedup vs baseline: 1.0880x; 1.0880x over previous
//
#include <hip/hip_runtime.h>
#include <math.h>

// ToRGB: y[b,o,p] = clip( sum_i coeff[b,o,i]*x[b,i,p] + bias[o], +-256 ) + upsample2(skip)
// x: (8,512,128,128) f32; out: (8,3,128,128) f32
// coeff[b,o,i] = weight[o,i]/512 * lrelu(w[b,:]@affine_w[i,:]/sqrt(512) + affine_b[i]) * sqrt(2)

#define IN_CH 512
#define OUT_CH 3
#define NPIX 16384    // 128*128
#define NB 8

// ---------------- Kernel 1: styles -> coeff (tiny, now 512 blocks) ----------------
// grid: 8 batches * 64 row-groups; each block does 8 rows (2 per wave).
__global__ __launch_bounds__(256) void coeff_kernel(
    const float* __restrict__ w, const float* __restrict__ aw,
    const float* __restrict__ ab, const float* __restrict__ wt,
    float* __restrict__ coeff) {
  const int b  = blockIdx.x >> 6;   // 8 batches
  const int rg = blockIdx.x & 63;   // 64 row-groups of 8 rows
  const int tid = threadIdx.x;
  __shared__ float wv[512];
  wv[tid]       = w[b * 512 + tid];
  wv[tid + 256] = w[b * 512 + 256 + tid];
  __syncthreads();
  const int wave = tid >> 6, lane = tid & 63;
  const float gain = 1.0f / sqrtf(512.0f);
  #pragma unroll
  for (int r = 0; r < 2; ++r) {
    const int i = rg * 8 + wave * 2 + r;
    const float* row = aw + (size_t)i * 512;
    float s = 0.f;
    #pragma unroll
    for (int k = 0; k < 8; ++k) s += row[lane + 64 * k] * wv[lane + 64 * k];
    #pragma unroll
    for (int off = 32; off >= 1; off >>= 1) s += __shfl_xor(s, off, 64);
    if (lane == 0) {
      float v = s * gain + ab[i];
      v = (v > 0.f ? v : 0.2f * v) * 1.41421356237f;  // lrelu * sqrt(2)
      #pragma unroll
      for (int o = 0; o < OUT_CH; ++o)
        coeff[b * (OUT_CH * IN_CH) + o * IN_CH + i] =
            wt[o * IN_CH + i] * (1.0f / 512.0f) * v;
    }
  }
}

// ---------------- Kernel 2: main reduction + epilogue ----------------
// grid: 8 batches * 256 pixel-groups (64 px each). block: 256 = 16 cols(x4 px) * 16 splits(32 ch)
__global__ __launch_bounds__(256) void main_kernel(
    const float* __restrict__ x, const float* __restrict__ coeff,
    const float* __restrict__ bias, const float* __restrict__ skip,
    float* __restrict__ out) {
  const int b   = blockIdx.x >> 8;
  const int g   = blockIdx.x & 255;
  const int p0  = g * 64;
  const int tid = threadIdx.x;
  const int col   = tid & 15;   // float4 column within 64-pixel group
  const int split = tid >> 4;   // channel split, 32 channels each

  // coeff staged per-split, packed [split][k][4] -> one ds_read_b128 per k
  __shared__ float lds_c[16 * 32 * 4];  // 8 KB
  for (int idx = tid; idx < 2048; idx += 256) {
    const int s = idx >> 7, rem = idx & 127, k = rem >> 2, o = rem & 3;
    lds_c[idx] = (o < 3)
        ? coeff[b * (OUT_CH * IN_CH) + o * IN_CH + s * 32 + k]
        : 0.f;
  }

  // ---- skip upsample computed EARLY (hides skip HBM latency under main loop) ----
  float up = 0.f;
  if (tid < 192) {
    const int o = tid >> 6;
    const int l = tid & 63;
    const int p = p0 + l;
    const int yy = p >> 7, xx = p & 127;
    int iy0, ix0; float wy0, wy1, wx0, wx1;
    if (yy & 1) { iy0 = (yy - 1) >> 1; wy0 = 3.f; wy1 = 1.f; }
    else        { iy0 = (yy >> 1) - 1; wy0 = 1.f; wy1 = 3.f; }
    if (xx & 1) { ix0 = (xx - 1) >> 1; wx0 = 3.f; wx1 = 1.f; }
    else        { ix0 = (xx >> 1) - 1; wx0 = 1.f; wx1 = 3.f; }
    const float* sp = skip + ((size_t)(b * OUT_CH + o)) * 4096;
    float s00 = (iy0 >= 0     && ix0 >= 0    ) ? sp[iy0 * 64 + ix0]           : 0.f;
    float s01 = (iy0 >= 0     && ix0 + 1 < 64) ? sp[iy0 * 64 + ix0 + 1]       : 0.f;
    float s10 = (iy0 + 1 < 64 && ix0 >= 0    ) ? sp[(iy0 + 1) * 64 + ix0]     : 0.f;
    float s11 = (iy0 + 1 < 64 && ix0 + 1 < 64) ? sp[(iy0 + 1) * 64 + ix0 + 1] : 0.f;
    up = (wy0 * (wx0 * s00 + wx1 * s01) + wy1 * (wx0 * s10 + wx1 * s11)) * (1.f / 16.f);
  }

  __syncthreads();

  const float* xp = x + ((size_t)(b * IN_CH + split * 32)) * NPIX + p0 + col * 4;
  const float* cp = lds_c + split * 128;

  float acc[12];
  #pragma unroll
  for (int j = 0; j < 12; ++j) acc[j] = 0.f;

  #pragma unroll 8
  for (int k = 0; k < 32; ++k) {
    float4 xv = *reinterpret_cast<const float4*>(xp + (size_t)k * NPIX);
    float4 c4 = *reinterpret_cast<const float4*>(cp + k * 4);
    acc[0] += c4.x * xv.x; acc[1]  += c4.x * xv.y; acc[2]  += c4.x * xv.z; acc[3]  += c4.x * xv.w;
    acc[4] += c4.y * xv.x; acc[5]  += c4.y * xv.y; acc[6]  += c4.y * xv.z; acc[7]  += c4.y * xv.w;
    acc[8] += c4.z * xv.x; acc[9]  += c4.z * xv.y; acc[10] += c4.z * xv.z; acc[11] += c4.z * xv.w;
  }

  // ---- cross-lane reduce: 4 splits per wave folded with 2 shfl_xor rounds ----
  #pragma unroll
  for (int j = 0; j < 12; ++j) {
    acc[j] += __shfl_xor(acc[j], 16, 64);
    acc[j] += __shfl_xor(acc[j], 32, 64);
  }
  // now lanes 0-15 of each wave hold the sum over its 4 splits
  __shared__ float red[4][16][13];  // stride 13: conflict-free
  const int wave = tid >> 6, lane = tid & 63;
  if (lane < 16) {
    #pragma unroll
    for (int j = 0; j < 12; ++j) red[wave][lane][j] = acc[j];
  }
  __syncthreads();

  // epilogue: 192 threads write 3 channels * 64 pixels
  if (tid < 192) {
    const int o = tid >> 6;
    const int l = tid & 63;
    const int c = l >> 2, j = o * 4 + (l & 3);
    float v = red[0][c][j] + red[1][c][j] + red[2][c][j] + red[3][c][j] + bias[o];
    v = fminf(fmaxf(v, -256.f), 256.f);
    out[((size_t)(b * OUT_CH + o)) * NPIX + p0 + l] = v + up;
  }
}

extern "C" void kernel_launch(void* const* d_in, const int* in_sizes, int n_in,
                              void* d_out, int out_size, void* d_ws, size_t ws_size,
                              hipStream_t stream) {
  const float* x        = (const float*)d_in[0];
  const float* w        = (const float*)d_in[1];
  const float* skip     = (const float*)d_in[2];
  const float* affine_w = (const float*)d_in[3];
  const float* affine_b = (const float*)d_in[4];
  const float* weight   = (const float*)d_in[5];
  const float* bias     = (const float*)d_in[6];
  float* out   = (float*)d_out;
  float* coeff = (float*)d_ws;  // 8*3*512 floats = 48 KB

  coeff_kernel<<<512, 256, 0, stream>>>(w, affine_w, affine_b, weight, coeff);
  main_kernel<<<NB * 256, 256, 0, stream>>>(x, coeff, bias, skip, out);
}